// Round 15
// baseline (75.259 us; speedup 1.0000x reference)
//
#include <hip/hip_runtime.h>
#include <hip/hip_fp16.h>

// Adaptive downsampler: B=8, C=3, 1024x1024 -> 512x512, K2=9 taps,
// bilinear gather from reflect-padded (pad=1) image, weighted by kernels.
// R15 = R14 (fp16 packed-pair LDS window, 512-thr/64x8 patch, 27-wide nt
//       preload, XCD slab swizzle, plain stores)
//       + BRANCHLESS fast path: phase A computes all 9 taps' clamped LDS
//       indices + miss-masked weights (no control flow); phase B issues all
//       27 ds_read2+FMA unconditionally -> scheduler can batch LDS reads
//       (R14 diagnosis: per-tap if/else exec-mask regions blocked hoisting;
//       duty cycle 8/(100+8)*6 waves ~= measured 43% VALUBusy).
//       Rare exact fp32 fallback in one cold __any-guarded block.
constexpr int B_  = 8;
constexpr int C_  = 3;
constexpr int H_  = 1024;
constexpr int W_  = 1024;
constexpr int HO_ = 512;
constexpr int WO_ = 512;
constexpr int K2_ = 9;
constexpr int KS_ = 3;
constexpr int HP_ = H_ + 2;   // padded height (pad=1)
constexpr int WP_ = W_ + 2;   // padded width
constexpr int TPB_  = 512;
constexpr int NBLK_ = (B_ * HO_ * WO_) / TPB_;  // 4096 blocks
constexpr int NXCD_ = 8;

// LDS window: WY_ rows x WX_ pair-cols x 3 channels (half2 per entry)
constexpr int WY_  = 30;
constexpr int WX_  = 144;
constexpr int WX4_ = WX_ / 4;              // 36 staging units per row
constexpr int WCH_ = WY_ * WX_;            // 4320 entries per channel
constexpr int NF4_ = 3 * WY_ * WX4_;       // 3240 staging units

__device__ __forceinline__ float2 ld2(const float* p) {
    float2 r;
    __builtin_memcpy(&r, p, sizeof(float2));   // global_load_dwordx2
    return r;
}

__global__ __launch_bounds__(TPB_) void ds_kernel(
    const float* __restrict__ img,
    const float* __restrict__ kern,
    const float* __restrict__ offh,
    const float* __restrict__ offv,
    const float* __restrict__ unit_p,
    float* __restrict__ out)
{
    const int HWo = HO_ * WO_;                       // 262144
    __shared__ __half2 shp[3 * WCH_];                // 51840 B

    // XCD swizzle: block i runs on XCD i%8; contiguous 512-block slab
    // per XCD = one batch, oy-ordered -> image window L2-resident.
    const int wg  = blockIdx.x;
    const int nid = (wg & (NXCD_ - 1)) * (NBLK_ / NXCD_) + (wg >> 3);

    // 2D patch decode: nid = b*512 + oyt*8 + oxt
    const int b   = nid >> 9;
    const int q   = nid & 511;
    const int oyt = q >> 3;             // 0..63: 8-row oy group
    const int oxt = q & 7;              // 0..7:  64-px ox chunk
    const int wv  = threadIdx.x >> 6;   // 0..7
    const int ln  = threadIdx.x & 63;
    const int oy  = oyt * 8 + wv;
    const int ox  = oxt * 64 + ln;

    const float unit = unit_p[0];
    const float* imgb = img + (size_t)b * (C_ * H_ * W_);
    const int kbase = b * (K2_ * HWo) + oy * WO_ + ox;   // < 2^25

    // Window origin (orig-image coords), x 4-aligned for float4 staging.
    int wxlo = 128 * oxt - 8;
    wxlo = wxlo < 0 ? 0 : (wxlo > W_ - WX_ ? W_ - WX_ : wxlo);   // 0..880, %4==0
    int wylo = 16 * oyt - 7;
    wylo = wylo < 0 ? 0 : (wylo > H_ - WY_ ? H_ - WY_ : wylo);   // 0..994

    // Phase 1: all 27 stream loads in flight (read-once -> nontemporal).
    float wk[K2_], oh[K2_], ov[K2_];
#pragma unroll
    for (int k = 0; k < K2_; ++k) {
        wk[k] = __builtin_nontemporal_load(kern + kbase + k * HWo);
        oh[k] = __builtin_nontemporal_load(offh + kbase + k * HWo);
        ov[k] = __builtin_nontemporal_load(offv + kbase + k * HWo);
    }

    // Phase 2: stage window into LDS as packed pairs:
    // shp[ch][row][c] = half2(img[row][c], img[row][c+1]).
#pragma unroll
    for (int i = 0; i < 7; ++i) {
        const int it = threadIdx.x + i * TPB_;
        if (it < NF4_) {
            const int ch  = it / (WY_ * WX4_);
            const int rem = it - ch * (WY_ * WX4_);
            const int row = rem / WX4_;
            const int c4  = rem - row * WX4_;
            const float* src = imgb + ch * (H_ * W_) + (wylo + row) * W_ + wxlo;
            const float4 v = ((const float4*)src)[c4];
            int gx = 4 * c4 + 4;                       // next element
            gx = (wxlo + gx > W_ - 1) ? (W_ - 1 - wxlo) : gx;  // clamp (unread pair)
            const float nx = src[gx];
            __half2 p0 = __float22half2_rn(make_float2(v.x, v.y));
            __half2 p1 = __float22half2_rn(make_float2(v.y, v.z));
            __half2 p2 = __float22half2_rn(make_float2(v.z, v.w));
            __half2 p3 = __float22half2_rn(make_float2(v.w, nx));
            __half2* dst = shp + ch * WCH_ + row * WX_ + 4 * c4;
            dst[0] = p0; dst[1] = p1; dst[2] = p2; dst[3] = p3;
        }
    }
    __syncthreads();

    // (ox+0.5)/WO*W - 0.5 == 2*ox + 0.5  (exact in fp32; W/WO = 2)
    const float cx = 2.0f * (float)ox + 0.5f;
    const float cy = 2.0f * (float)oy + 0.5f;

    // Phase A: per-tap index/weight precompute, branchless; miss-mask.
    int   idx[K2_];
    float axr[K2_];                  // alpha (right weight)
    float wtm[K2_], wbm[K2_];        // top/bottom weights, zeroed if miss
    unsigned miss = 0u;
#pragma unroll
    for (int k = 0; k < K2_; ++k) {
        const float px = cx + (float)(k % KS_) + oh[k] * unit;
        const float py = cy + (float)(k / KS_) + ov[k] * unit;
        const float fx = floorf(px);
        const float fy = floorf(py);
        const float a  = px - fx;
        const float bt = py - fy;
        const int x0 = (int)fx - 1;
        const int y0 = (int)fy - 1;

        const bool inwin = (x0 >= wxlo) & (x0 <= wxlo + WX_ - 2)
                         & (y0 >= wylo) & (y0 <= wylo + WY_ - 2);
        // clamp into window (safe LDS read; weight zeroed if miss)
        int xc = x0 < wxlo ? wxlo : (x0 > wxlo + WX_ - 2 ? wxlo + WX_ - 2 : x0);
        int yc = y0 < wylo ? wylo : (y0 > wylo + WY_ - 2 ? wylo + WY_ - 2 : y0);
        idx[k] = (yc - wylo) * WX_ + (xc - wxlo);
        axr[k] = a;
        const float wt = wk[k] * (1.0f - bt);
        const float wb = wk[k] * bt;
        wtm[k] = inwin ? wt : 0.0f;
        wbm[k] = inwin ? wb : 0.0f;
        miss |= (inwin ? 0u : 1u) << k;
    }

    float acc0 = 0.0f, acc1 = 0.0f, acc2 = 0.0f;

    // Phase B: branchless LDS consumption — all reads hoistable.
#pragma unroll
    for (int k = 0; k < K2_; ++k) {
        const float ax1 = axr[k];
        const float ax0 = 1.0f - ax1;
        const float wt = wtm[k], wb = wbm[k];
        const int i_t = idx[k];
        {
            const float2 t = __half22float2(shp[i_t]);
            const float2 u = __half22float2(shp[i_t + WX_]);
            acc0 = fmaf(wt, fmaf(ax0, t.x, ax1 * t.y),
                   fmaf(wb, fmaf(ax0, u.x, ax1 * u.y), acc0));
        }
        {
            const float2 t = __half22float2(shp[WCH_ + i_t]);
            const float2 u = __half22float2(shp[WCH_ + i_t + WX_]);
            acc1 = fmaf(wt, fmaf(ax0, t.x, ax1 * t.y),
                   fmaf(wb, fmaf(ax0, u.x, ax1 * u.y), acc1));
        }
        {
            const float2 t = __half22float2(shp[2 * WCH_ + i_t]);
            const float2 u = __half22float2(shp[2 * WCH_ + i_t + WX_]);
            acc2 = fmaf(wt, fmaf(ax0, t.x, ax1 * t.y),
                   fmaf(wb, fmaf(ax0, u.x, ax1 * u.y), acc2));
        }
    }

    // Cold exact fallback: add the exact fp32 contribution of missed taps
    // (their masked weights contributed exactly 0 above).
    if (__any(miss != 0u)) {
#pragma unroll
        for (int k = 0; k < K2_; ++k) {
            if (miss & (1u << k)) {
                const float px = cx + (float)(k % KS_) + oh[k] * unit;
                const float py = cy + (float)(k / KS_) + ov[k] * unit;
                const float fx = floorf(px);
                const float fy = floorf(py);
                const float a  = px - fx;
                const float bt = py - fy;

                int xL = (int)fx; xL = xL < 0 ? 0 : (xL > WP_ - 1 ? WP_ - 1 : xL);
                int xR = xL + 1;  xR = xR > WP_ - 1 ? WP_ - 1 : xR;
                int yT = (int)fy; yT = yT < 0 ? 0 : (yT > HP_ - 1 ? HP_ - 1 : yT);
                int yB = yT + 1;  yB = yB > HP_ - 1 ? HP_ - 1 : yB;

                int xl = xL - 1; xl = (xl < 0) ? -xl : (xl >= W_ ? 2 * W_ - 2 - xl : xl);
                int xr = xR - 1; xr = (xr < 0) ? -xr : (xr >= W_ ? 2 * W_ - 2 - xr : xr);
                int yt = yT - 1; yt = (yt < 0) ? -yt : (yt >= H_ ? 2 * H_ - 2 - yt : yt);
                int yb = yB - 1; yb = (yb < 0) ? -yb : (yb >= H_ ? 2 * H_ - 2 - yb : yb);

                const int base = xl < xr ? xl : xr;
                const float ax0 = ((xl == base) ? (1.0f - a) : 0.0f)
                                + ((xr == base) ? a : 0.0f);
                const float ax1 = 1.0f - ax0;
                const float wt = wk[k] * (1.0f - bt);
                const float wb = wk[k] * bt;

                const int r0 = yt * W_ + base;
                const int r1 = yb * W_ + base;
                {
                    const float2 v = ld2(imgb + r0);
                    const float2 u = ld2(imgb + r1);
                    acc0 = fmaf(wt, fmaf(ax0, v.x, ax1 * v.y),
                           fmaf(wb, fmaf(ax0, u.x, ax1 * u.y), acc0));
                }
                {
                    const float2 v = ld2(imgb + H_ * W_ + r0);
                    const float2 u = ld2(imgb + H_ * W_ + r1);
                    acc1 = fmaf(wt, fmaf(ax0, v.x, ax1 * v.y),
                           fmaf(wb, fmaf(ax0, u.x, ax1 * u.y), acc1));
                }
                {
                    const float2 v = ld2(imgb + 2 * H_ * W_ + r0);
                    const float2 u = ld2(imgb + 2 * H_ * W_ + r1);
                    acc2 = fmaf(wt, fmaf(ax0, v.x, ax1 * v.y),
                           fmaf(wb, fmaf(ax0, u.x, ax1 * u.y), acc2));
                }
            }
        }
    }

    const int obase = b * (C_ * HWo) + oy * WO_ + ox;
    out[obase]           = acc0;
    out[obase + HWo]     = acc1;
    out[obase + 2 * HWo] = acc2;
}

extern "C" void kernel_launch(void* const* d_in, const int* in_sizes, int n_in,
                              void* d_out, int out_size, void* d_ws, size_t ws_size,
                              hipStream_t stream) {
    const float* img  = (const float*)d_in[0];
    const float* kern = (const float*)d_in[1];
    const float* offh = (const float*)d_in[2];
    const float* offv = (const float*)d_in[3];
    const float* unit = (const float*)d_in[4];
    float* out = (float*)d_out;

    ds_kernel<<<NBLK_, TPB_, 0, stream>>>(img, kern, offh, offv, unit, out);
}

// Round 16
// 72.464 us; speedup vs baseline: 1.0386x; 1.0386x over previous
//
#include <hip/hip_runtime.h>
#include <hip/hip_fp16.h>

// Adaptive downsampler: B=8, C=3, 1024x1024 -> 512x512, K2=9 taps,
// bilinear gather from reflect-padded (pad=1) image, weighted by kernels.
// R16 = R14 (71.9us: fp16 packed-pair LDS window, branchy lean fast path +
//       exact fp32 fallback, 512-thr/64x8 patch, 27-wide nt preload, XCD
//       slab swizzle, plain stores)
//       + window shrunk 30x144 -> 25x136 (40,960B alloc): EXACTLY 4 blocks/
//       CU (4x40960 = 160KiB) -> 32 waves/CU occupancy cap (was 3 blocks/
//       75%, measured 46%). Margins ~±3.5σ; rare taps fall back (exact).
constexpr int B_  = 8;
constexpr int C_  = 3;
constexpr int H_  = 1024;
constexpr int W_  = 1024;
constexpr int HO_ = 512;
constexpr int WO_ = 512;
constexpr int K2_ = 9;
constexpr int KS_ = 3;
constexpr int HP_ = H_ + 2;   // padded height (pad=1)
constexpr int WP_ = W_ + 2;   // padded width
constexpr int TPB_  = 512;
constexpr int NBLK_ = (B_ * HO_ * WO_) / TPB_;  // 4096 blocks
constexpr int NXCD_ = 8;

// LDS window: WY_ rows x WX_ pair-cols x 3 channels (half2 per entry)
constexpr int WY_  = 25;
constexpr int WX_  = 136;
constexpr int WX4_ = WX_ / 4;              // 34 staging units per row
constexpr int WCH_ = WY_ * WX_;            // 3400 entries per channel
constexpr int NF4_ = 3 * WY_ * WX4_;       // 2550 staging units

__device__ __forceinline__ float2 ld2(const float* p) {
    float2 r;
    __builtin_memcpy(&r, p, sizeof(float2));   // global_load_dwordx2
    return r;
}

__global__ __launch_bounds__(TPB_) void ds_kernel(
    const float* __restrict__ img,
    const float* __restrict__ kern,
    const float* __restrict__ offh,
    const float* __restrict__ offv,
    const float* __restrict__ unit_p,
    float* __restrict__ out)
{
    const int HWo = HO_ * WO_;                       // 262144
    __shared__ __half2 shp[3 * WCH_];                // 40800 B -> 40960 alloc

    // XCD swizzle: block i runs on XCD i%8; contiguous 512-block slab
    // per XCD = one batch, oy-ordered -> image window L2-resident.
    const int wg  = blockIdx.x;
    const int nid = (wg & (NXCD_ - 1)) * (NBLK_ / NXCD_) + (wg >> 3);

    // 2D patch decode: nid = b*512 + oyt*8 + oxt
    const int b   = nid >> 9;
    const int q   = nid & 511;
    const int oyt = q >> 3;             // 0..63: 8-row oy group
    const int oxt = q & 7;              // 0..7:  64-px ox chunk
    const int wv  = threadIdx.x >> 6;   // 0..7
    const int ln  = threadIdx.x & 63;
    const int oy  = oyt * 8 + wv;
    const int ox  = oxt * 64 + ln;

    const float unit = unit_p[0];
    const float* imgb = img + (size_t)b * (C_ * H_ * W_);
    const int kbase = b * (K2_ * HWo) + oy * WO_ + ox;   // < 2^25

    // Window origin (orig-image coords), x 4-aligned for float4 staging.
    int wxlo = 128 * oxt - 4;
    wxlo = wxlo < 0 ? 0 : (wxlo > W_ - WX_ ? W_ - WX_ : wxlo);   // 0..888, %4==0
    int wylo = 16 * oyt - 4;
    wylo = wylo < 0 ? 0 : (wylo > H_ - WY_ ? H_ - WY_ : wylo);   // 0..999

    // Phase 1: all 27 stream loads in flight (read-once -> nontemporal).
    float wk[K2_], oh[K2_], ov[K2_];
#pragma unroll
    for (int k = 0; k < K2_; ++k) {
        wk[k] = __builtin_nontemporal_load(kern + kbase + k * HWo);
        oh[k] = __builtin_nontemporal_load(offh + kbase + k * HWo);
        ov[k] = __builtin_nontemporal_load(offv + kbase + k * HWo);
    }

    // Phase 2: stage window into LDS as packed pairs:
    // shp[ch][row][c] = half2(img[row][c], img[row][c+1]).
#pragma unroll
    for (int i = 0; i < 5; ++i) {
        const int it = threadIdx.x + i * TPB_;
        if (it < NF4_) {
            const int ch  = it / (WY_ * WX4_);
            const int rem = it - ch * (WY_ * WX4_);
            const int row = rem / WX4_;
            const int c4  = rem - row * WX4_;
            const float* src = imgb + ch * (H_ * W_) + (wylo + row) * W_ + wxlo;
            const float4 v = ((const float4*)src)[c4];
            int gx = 4 * c4 + 4;                       // next element
            gx = (wxlo + gx > W_ - 1) ? (W_ - 1 - wxlo) : gx;  // clamp (unread pair)
            const float nx = src[gx];
            __half2 p0 = __float22half2_rn(make_float2(v.x, v.y));
            __half2 p1 = __float22half2_rn(make_float2(v.y, v.z));
            __half2 p2 = __float22half2_rn(make_float2(v.z, v.w));
            __half2 p3 = __float22half2_rn(make_float2(v.w, nx));
            __half2* dst = shp + ch * WCH_ + row * WX_ + 4 * c4;
            dst[0] = p0; dst[1] = p1; dst[2] = p2; dst[3] = p3;
        }
    }
    __syncthreads();

    // (ox+0.5)/WO*W - 0.5 == 2*ox + 0.5  (exact in fp32; W/WO = 2)
    const float cx = 2.0f * (float)ox + 0.5f;
    const float cy = 2.0f * (float)oy + 0.5f;

    float acc0 = 0.0f, acc1 = 0.0f, acc2 = 0.0f;

    // Phase 3: taps, fully unrolled; packed LDS fast path + exact fallback.
#pragma unroll
    for (int k = 0; k < K2_; ++k) {
        const float px = cx + (float)(k % KS_) + oh[k] * unit;
        const float py = cy + (float)(k / KS_) + ov[k] * unit;

        const float fx = floorf(px);
        const float fy = floorf(py);
        const float a  = px - fx;   // alpha
        const float bt = py - fy;   // beta

        // raw corner (orig coords); if in window, clip is inactive and
        // reflect is identity (window subset of [0,W-1]x[0,H-1]).
        const int x0 = (int)fx - 1;
        const int y0 = (int)fy - 1;

        const float wt = wk[k] * (1.0f - bt);
        const float wb = wk[k] * bt;

        const bool inwin = (x0 >= wxlo) & (x0 <= wxlo + WX_ - 2)
                         & (y0 >= wylo) & (y0 <= wylo + WY_ - 2);

        if (inwin) {
            const float ax0 = 1.0f - a;
            const float ax1 = a;
            const int i_t = (y0 - wylo) * WX_ + (x0 - wxlo);
            {
                const __half2* hp = shp;
                const float2 t = __half22float2(hp[i_t]);
                const float2 u = __half22float2(hp[i_t + WX_]);
                acc0 = fmaf(wt, fmaf(ax0, t.x, ax1 * t.y),
                       fmaf(wb, fmaf(ax0, u.x, ax1 * u.y), acc0));
            }
            {
                const __half2* hp = shp + WCH_;
                const float2 t = __half22float2(hp[i_t]);
                const float2 u = __half22float2(hp[i_t + WX_]);
                acc1 = fmaf(wt, fmaf(ax0, t.x, ax1 * t.y),
                       fmaf(wb, fmaf(ax0, u.x, ax1 * u.y), acc1));
            }
            {
                const __half2* hp = shp + 2 * WCH_;
                const float2 t = __half22float2(hp[i_t]);
                const float2 u = __half22float2(hp[i_t + WX_]);
                acc2 = fmaf(wt, fmaf(ax0, t.x, ax1 * t.y),
                       fmaf(wb, fmaf(ax0, u.x, ax1 * u.y), acc2));
            }
        } else {
            // exact reference semantics: clip in padded coords + reflect,
            // fp32 global reads (precision preserved for outliers).
            int xL = (int)fx; xL = xL < 0 ? 0 : (xL > WP_ - 1 ? WP_ - 1 : xL);
            int xR = xL + 1;  xR = xR > WP_ - 1 ? WP_ - 1 : xR;
            int yT = (int)fy; yT = yT < 0 ? 0 : (yT > HP_ - 1 ? HP_ - 1 : yT);
            int yB = yT + 1;  yB = yB > HP_ - 1 ? HP_ - 1 : yB;

            int xl = xL - 1; xl = (xl < 0) ? -xl : (xl >= W_ ? 2 * W_ - 2 - xl : xl);
            int xr = xR - 1; xr = (xr < 0) ? -xr : (xr >= W_ ? 2 * W_ - 2 - xr : xr);
            int yt = yT - 1; yt = (yt < 0) ? -yt : (yt >= H_ ? 2 * H_ - 2 - yt : yt);
            int yb = yB - 1; yb = (yb < 0) ? -yb : (yb >= H_ ? 2 * H_ - 2 - yb : yb);

            const int base = xl < xr ? xl : xr;
            const float ax0 = ((xl == base) ? (1.0f - a) : 0.0f)
                            + ((xr == base) ? a : 0.0f);
            const float ax1 = 1.0f - ax0;

            const int r0 = yt * W_ + base;
            const int r1 = yb * W_ + base;
            {
                const float2 v = ld2(imgb + r0);
                const float2 u = ld2(imgb + r1);
                acc0 = fmaf(wt, fmaf(ax0, v.x, ax1 * v.y),
                       fmaf(wb, fmaf(ax0, u.x, ax1 * u.y), acc0));
            }
            {
                const float2 v = ld2(imgb + H_ * W_ + r0);
                const float2 u = ld2(imgb + H_ * W_ + r1);
                acc1 = fmaf(wt, fmaf(ax0, v.x, ax1 * v.y),
                       fmaf(wb, fmaf(ax0, u.x, ax1 * u.y), acc1));
            }
            {
                const float2 v = ld2(imgb + 2 * H_ * W_ + r0);
                const float2 u = ld2(imgb + 2 * H_ * W_ + r1);
                acc2 = fmaf(wt, fmaf(ax0, v.x, ax1 * v.y),
                       fmaf(wb, fmaf(ax0, u.x, ax1 * u.y), acc2));
            }
        }
    }

    const int obase = b * (C_ * HWo) + oy * WO_ + ox;
    out[obase]           = acc0;
    out[obase + HWo]     = acc1;
    out[obase + 2 * HWo] = acc2;
}

extern "C" void kernel_launch(void* const* d_in, const int* in_sizes, int n_in,
                              void* d_out, int out_size, void* d_ws, size_t ws_size,
                              hipStream_t stream) {
    const float* img  = (const float*)d_in[0];
    const float* kern = (const float*)d_in[1];
    const float* offh = (const float*)d_in[2];
    const float* offv = (const float*)d_in[3];
    const float* unit = (const float*)d_in[4];
    float* out = (float*)d_out;

    ds_kernel<<<NBLK_, TPB_, 0, stream>>>(img, kern, offh, offv, unit, out);
}

// Round 17
// 66.023 us; speedup vs baseline: 1.1399x; 1.0976x over previous
//
#include <hip/hip_runtime.h>
#include <hip/hip_fp16.h>

// Adaptive downsampler: B=8, C=3, 1024x1024 -> 512x512, K2=9 taps,
// bilinear gather from reflect-padded (pad=1) image, weighted by kernels.
// R17 = R16 (72.5us: fp16 packed-pair LDS 25x136x3 window = 40960B alloc,
//       branchy lean fast path + exact fp32 fallback, 512-thr/64x8 patch,
//       27-wide nt preload, XCD slab swizzle, plain stores)
//       + v_dot2_f32_f16 bilinear: per tap fold row weights into 2 packed
//       half2 vectors (cvt_pkrtz), then each channel = 1 ds_read2 + 2 fdot2
//       (was 4 cvt + 5 fma). Tap VALU -33%. fp16 weight quantization adds
//       ~2e-3 error (absmax 0.031 -> ~0.05, threshold 0.215).
constexpr int B_  = 8;
constexpr int C_  = 3;
constexpr int H_  = 1024;
constexpr int W_  = 1024;
constexpr int HO_ = 512;
constexpr int WO_ = 512;
constexpr int K2_ = 9;
constexpr int KS_ = 3;
constexpr int HP_ = H_ + 2;   // padded height (pad=1)
constexpr int WP_ = W_ + 2;   // padded width
constexpr int TPB_  = 512;
constexpr int NBLK_ = (B_ * HO_ * WO_) / TPB_;  // 4096 blocks
constexpr int NXCD_ = 8;

// LDS window: WY_ rows x WX_ pair-cols x 3 channels (half2 per entry)
constexpr int WY_  = 25;
constexpr int WX_  = 136;
constexpr int WX4_ = WX_ / 4;              // 34 staging units per row
constexpr int WCH_ = WY_ * WX_;            // 3400 entries per channel
constexpr int NF4_ = 3 * WY_ * WX4_;       // 2550 staging units

typedef __fp16 h2v __attribute__((ext_vector_type(2)));

__device__ __forceinline__ float2 ld2(const float* p) {
    float2 r;
    __builtin_memcpy(&r, p, sizeof(float2));   // global_load_dwordx2
    return r;
}

__device__ __forceinline__ h2v ldh2(const __half2* p) {
    h2v r;
    __builtin_memcpy(&r, p, sizeof(h2v));      // ds_read_b32 (paired by compiler)
    return r;
}

__global__ __launch_bounds__(TPB_) void ds_kernel(
    const float* __restrict__ img,
    const float* __restrict__ kern,
    const float* __restrict__ offh,
    const float* __restrict__ offv,
    const float* __restrict__ unit_p,
    float* __restrict__ out)
{
    const int HWo = HO_ * WO_;                       // 262144
    __shared__ __half2 shp[3 * WCH_];                // 40800 B -> 40960 alloc

    // XCD swizzle: block i runs on XCD i%8; contiguous 512-block slab
    // per XCD = one batch, oy-ordered -> image window L2-resident.
    const int wg  = blockIdx.x;
    const int nid = (wg & (NXCD_ - 1)) * (NBLK_ / NXCD_) + (wg >> 3);

    // 2D patch decode: nid = b*512 + oyt*8 + oxt
    const int b   = nid >> 9;
    const int q   = nid & 511;
    const int oyt = q >> 3;             // 0..63: 8-row oy group
    const int oxt = q & 7;              // 0..7:  64-px ox chunk
    const int wv  = threadIdx.x >> 6;   // 0..7
    const int ln  = threadIdx.x & 63;
    const int oy  = oyt * 8 + wv;
    const int ox  = oxt * 64 + ln;

    const float unit = unit_p[0];
    const float* imgb = img + (size_t)b * (C_ * H_ * W_);
    const int kbase = b * (K2_ * HWo) + oy * WO_ + ox;   // < 2^25

    // Window origin (orig-image coords), x 4-aligned for float4 staging.
    int wxlo = 128 * oxt - 4;
    wxlo = wxlo < 0 ? 0 : (wxlo > W_ - WX_ ? W_ - WX_ : wxlo);   // 0..888, %4==0
    int wylo = 16 * oyt - 4;
    wylo = wylo < 0 ? 0 : (wylo > H_ - WY_ ? H_ - WY_ : wylo);   // 0..999

    // Phase 1: all 27 stream loads in flight (read-once -> nontemporal).
    float wk[K2_], oh[K2_], ov[K2_];
#pragma unroll
    for (int k = 0; k < K2_; ++k) {
        wk[k] = __builtin_nontemporal_load(kern + kbase + k * HWo);
        oh[k] = __builtin_nontemporal_load(offh + kbase + k * HWo);
        ov[k] = __builtin_nontemporal_load(offv + kbase + k * HWo);
    }

    // Phase 2: stage window into LDS as packed pairs:
    // shp[ch][row][c] = half2(img[row][c], img[row][c+1]).
#pragma unroll
    for (int i = 0; i < 5; ++i) {
        const int it = threadIdx.x + i * TPB_;
        if (it < NF4_) {
            const int ch  = it / (WY_ * WX4_);
            const int rem = it - ch * (WY_ * WX4_);
            const int row = rem / WX4_;
            const int c4  = rem - row * WX4_;
            const float* src = imgb + ch * (H_ * W_) + (wylo + row) * W_ + wxlo;
            const float4 v = ((const float4*)src)[c4];
            int gx = 4 * c4 + 4;                       // next element
            gx = (wxlo + gx > W_ - 1) ? (W_ - 1 - wxlo) : gx;  // clamp (unread pair)
            const float nx = src[gx];
            __half2 p0 = __float22half2_rn(make_float2(v.x, v.y));
            __half2 p1 = __float22half2_rn(make_float2(v.y, v.z));
            __half2 p2 = __float22half2_rn(make_float2(v.z, v.w));
            __half2 p3 = __float22half2_rn(make_float2(v.w, nx));
            __half2* dst = shp + ch * WCH_ + row * WX_ + 4 * c4;
            dst[0] = p0; dst[1] = p1; dst[2] = p2; dst[3] = p3;
        }
    }
    __syncthreads();

    // (ox+0.5)/WO*W - 0.5 == 2*ox + 0.5  (exact in fp32; W/WO = 2)
    const float cx = 2.0f * (float)ox + 0.5f;
    const float cy = 2.0f * (float)oy + 0.5f;

    float acc0 = 0.0f, acc1 = 0.0f, acc2 = 0.0f;

    // Phase 3: taps, fully unrolled; fdot2 LDS fast path + exact fallback.
#pragma unroll
    for (int k = 0; k < K2_; ++k) {
        const float px = cx + (float)(k % KS_) + oh[k] * unit;
        const float py = cy + (float)(k / KS_) + ov[k] * unit;

        const float fx = floorf(px);
        const float fy = floorf(py);
        const float a  = px - fx;   // alpha
        const float bt = py - fy;   // beta

        // raw corner (orig coords); if in window, clip is inactive and
        // reflect is identity (window subset of [0,W-1]x[0,H-1]).
        const int x0 = (int)fx - 1;
        const int y0 = (int)fy - 1;

        const float wt = wk[k] * (1.0f - bt);
        const float wb = wk[k] * bt;

        const bool inwin = (x0 >= wxlo) & (x0 <= wxlo + WX_ - 2)
                         & (y0 >= wylo) & (y0 <= wylo + WY_ - 2);

        if (inwin) {
            const float ax0 = 1.0f - a;
            // fold row weights into packed half2: one dot2 per row per ch
            const h2v axt = __builtin_amdgcn_cvt_pkrtz(wt * ax0, wt * a);
            const h2v axb = __builtin_amdgcn_cvt_pkrtz(wb * ax0, wb * a);
            const int i_t = (y0 - wylo) * WX_ + (x0 - wxlo);
            {
                const __half2* hp = shp;
                acc0 = __builtin_amdgcn_fdot2(ldh2(hp + i_t),       axt, acc0, false);
                acc0 = __builtin_amdgcn_fdot2(ldh2(hp + i_t + WX_), axb, acc0, false);
            }
            {
                const __half2* hp = shp + WCH_;
                acc1 = __builtin_amdgcn_fdot2(ldh2(hp + i_t),       axt, acc1, false);
                acc1 = __builtin_amdgcn_fdot2(ldh2(hp + i_t + WX_), axb, acc1, false);
            }
            {
                const __half2* hp = shp + 2 * WCH_;
                acc2 = __builtin_amdgcn_fdot2(ldh2(hp + i_t),       axt, acc2, false);
                acc2 = __builtin_amdgcn_fdot2(ldh2(hp + i_t + WX_), axb, acc2, false);
            }
        } else {
            // exact reference semantics: clip in padded coords + reflect,
            // fp32 global reads (precision preserved for outliers).
            int xL = (int)fx; xL = xL < 0 ? 0 : (xL > WP_ - 1 ? WP_ - 1 : xL);
            int xR = xL + 1;  xR = xR > WP_ - 1 ? WP_ - 1 : xR;
            int yT = (int)fy; yT = yT < 0 ? 0 : (yT > HP_ - 1 ? HP_ - 1 : yT);
            int yB = yT + 1;  yB = yB > HP_ - 1 ? HP_ - 1 : yB;

            int xl = xL - 1; xl = (xl < 0) ? -xl : (xl >= W_ ? 2 * W_ - 2 - xl : xl);
            int xr = xR - 1; xr = (xr < 0) ? -xr : (xr >= W_ ? 2 * W_ - 2 - xr : xr);
            int yt = yT - 1; yt = (yt < 0) ? -yt : (yt >= H_ ? 2 * H_ - 2 - yt : yt);
            int yb = yB - 1; yb = (yb < 0) ? -yb : (yb >= H_ ? 2 * H_ - 2 - yb : yb);

            const int base = xl < xr ? xl : xr;
            const float ax0 = ((xl == base) ? (1.0f - a) : 0.0f)
                            + ((xr == base) ? a : 0.0f);
            const float ax1 = 1.0f - ax0;

            const int r0 = yt * W_ + base;
            const int r1 = yb * W_ + base;
            {
                const float2 v = ld2(imgb + r0);
                const float2 u = ld2(imgb + r1);
                acc0 = fmaf(wt, fmaf(ax0, v.x, ax1 * v.y),
                       fmaf(wb, fmaf(ax0, u.x, ax1 * u.y), acc0));
            }
            {
                const float2 v = ld2(imgb + H_ * W_ + r0);
                const float2 u = ld2(imgb + H_ * W_ + r1);
                acc1 = fmaf(wt, fmaf(ax0, v.x, ax1 * v.y),
                       fmaf(wb, fmaf(ax0, u.x, ax1 * u.y), acc1));
            }
            {
                const float2 v = ld2(imgb + 2 * H_ * W_ + r0);
                const float2 u = ld2(imgb + 2 * H_ * W_ + r1);
                acc2 = fmaf(wt, fmaf(ax0, v.x, ax1 * v.y),
                       fmaf(wb, fmaf(ax0, u.x, ax1 * u.y), acc2));
            }
        }
    }

    const int obase = b * (C_ * HWo) + oy * WO_ + ox;
    out[obase]           = acc0;
    out[obase + HWo]     = acc1;
    out[obase + 2 * HWo] = acc2;
}

extern "C" void kernel_launch(void* const* d_in, const int* in_sizes, int n_in,
                              void* d_out, int out_size, void* d_ws, size_t ws_size,
                              hipStream_t stream) {
    const float* img  = (const float*)d_in[0];
    const float* kern = (const float*)d_in[1];
    const float* offh = (const float*)d_in[2];
    const float* offv = (const float*)d_in[3];
    const float* unit = (const float*)d_in[4];
    float* out = (float*)d_out;

    ds_kernel<<<NBLK_, TPB_, 0, stream>>>(img, kern, offh, offv, unit, out);
}